// Round 10
// baseline (2960.277 us; speedup 1.0000x reference)
//
#include <hip/hip_runtime.h>
#include <hip/hip_bf16.h>
#include <stdint.h>

// ExpanderLinear: y[t,o] = sum_i x[t,i] * (w[o,i]*mask[o,i]) + bias[o]
// M=8192, K=4096, N=4096. f32 in/out, bf16 MFMA compute.
// R10: 512x256 block tile, 8 waves (2/SIMD), per-wave 128x128 output.
// LDS amplification drops 3x -> 2x: per k-step-32, reads 1536 cyc vs MFMA
// 2483 cyc. Ring-3 x 48KB LDS (144 KiB), stage 2 units ahead, counted
// vmcnt(6)/iter, one barrier/iter, register double-buffered operands,
// next-unit reads interleaved between the two 32-MFMA halves. No SCHED0.

typedef __attribute__((ext_vector_type(4))) float          f32x4;
typedef __attribute__((ext_vector_type(4))) int            i32x4;
typedef __attribute__((ext_vector_type(4))) unsigned short u16x4;
typedef __attribute__((ext_vector_type(8))) __bf16         bf16x8;

static constexpr int M = 8192;
static constexpr int N = 4096;
static constexpr int K = 4096;

#define BMr 512
#define BNr 256

#define GLOBAL_AS(p) ((const __attribute__((address_space(1))) void*)(p))
#define LDS_AS(p)    ((__attribute__((address_space(3))) void*)(p))

__device__ __forceinline__ unsigned short f2bf(float f) {
    unsigned int u = __float_as_uint(f);
    u = (u + 0x7fffu + ((u >> 16) & 1u)) >> 16;
    return (unsigned short)u;
}

// ---- prep 1: x f32 -> bf16 ----
__global__ void cvt_x_kernel(const float* __restrict__ x,
                             unsigned short* __restrict__ out) {
    int i = blockIdx.x * blockDim.x + threadIdx.x;
    f32x4 v = ((const f32x4*)x)[i];
    u16x4 r;
    r.x = f2bf(v.x); r.y = f2bf(v.y); r.z = f2bf(v.z); r.w = f2bf(v.w);
    ((u16x4*)out)[i] = r;
}

// ---- prep 2: (w * mask) f32 -> bf16, fused ----
__global__ void cvt_wm_kernel(const float* __restrict__ w,
                              const int* __restrict__ mask,
                              unsigned short* __restrict__ out) {
    int i = blockIdx.x * blockDim.x + threadIdx.x;
    f32x4 v = ((const f32x4*)w)[i];
    i32x4 m = ((const i32x4*)mask)[i];
    u16x4 r;
    r.x = m.x ? f2bf(v.x) : (unsigned short)0;
    r.y = m.y ? f2bf(v.y) : (unsigned short)0;
    r.z = m.z ? f2bf(v.z) : (unsigned short)0;
    r.w = m.w ? f2bf(v.w) : (unsigned short)0;
    ((u16x4*)out)[i] = r;
}

// ---- main GEMM ----
// LDS slot (48KB): A [512 rows][32 bf16] (32KB) + B [256 rows][32 bf16] (16KB).
// Unit u (k in [32u,32u+32)) lives in slot u%3. Iter u: MM64 on unit-u regs
// (read at iter u-1), ds_read unit u+1, stage unit u+2 into slot (u+2)%3
// (= slot (u-1)%3, whose reads finished before iter u-1's MM; the iter-u
// barrier separates). WVM(6) retires the batch staged one iter ago.
// Swizzle (within 128B row-pair): phys3 = (((row&1)<<2)|fq) ^ ((row>>1)&7).
// LDS writes linear (global_load_lds); global SOURCE pre-swizzled.
__global__ void __launch_bounds__(512, 2)
gemmW_bf16(const unsigned short* __restrict__ A,   // [M][K] bf16 bits
           const unsigned short* __restrict__ B,   // [N][K] bf16 bits
           const float* __restrict__ bias,         // [N]
           float* __restrict__ C) {                // [M][N] f32
    extern __shared__ unsigned short lds[];        // 3 * 24576 ushorts

    const int tid  = threadIdx.x;
    const int lane = tid & 63;
    const int wave = tid >> 6;                     // 0..7

    // T1: XCD-aware bijective swizzle (nwg = 256, % 8 == 0)
    const int bid = blockIdx.x;
    const int swz = (bid & 7) * 32 + (bid >> 3);
    const int brow = (swz >> 4) * BMr;             // 16 col-tiles
    const int bcol = (swz & 15) * BNr;

    const int wrow = (wave >> 1) * 128;            // 0,128,256,384
    const int wcol = (wave & 1) * 128;             // 0,128
    const int fr = lane & 15;                      // fragment row/col
    const int fq = lane >> 4;                      // k-subgroup

    // read-side swizzle bases (byte offsets)
    const int s3r   = (((fr & 1) << 2) | fq) ^ (fr >> 1);
    const int abase = wrow * 64 + (fr >> 1) * 128 + s3r * 16;   // in A region
    const int bbase = wcol * 64 + (fr >> 1) * 128 + s3r * 16;   // in B region

    // write-side: lane's linear LDS slot -> logical (row, col) in global
    const int l8 = lane & 7, lh = lane >> 3;
    const int s3w    = l8 ^ lh;
    const int wrow_l = 2 * lh + (s3w >> 2);        // row within 16-row chunk
    const int wcol_l = (s3w & 3) * 8;              // bf16 col within 32-col unit

    const unsigned short* __restrict__ Ag = A + (size_t)brow * K;
    const unsigned short* __restrict__ Bg = B + (size_t)bcol * K;

    f32x4 acc[8][8];
#pragma unroll
    for (int m = 0; m < 8; ++m)
#pragma unroll
        for (int n = 0; n < 8; ++n) acc[m][n] = (f32x4)(0.0f);

    // double-buffered operand registers (static names, rule #20)
    bf16x8 paA[8], pbA[8], paB[8], pbB[8];

#define STG1(dst, src) __builtin_amdgcn_global_load_lds(GLOBAL_AS(src), LDS_AS(dst), 16, 0, 0)
// stage unit j into slot s: 4 A-loads + 2 B-loads per thread
#define STAGE(s, j) do {                                                        \
    _Pragma("unroll")                                                           \
    for (int c = 0; c < 4; ++c) {                                               \
        const int q_ = c * 8 + wave;                                            \
        STG1(lds + (s) * 24576 + q_ * 512,                                      \
             Ag + (size_t)(q_ * 16 + wrow_l) * K + (j) * 32 + wcol_l);          \
    }                                                                           \
    _Pragma("unroll")                                                           \
    for (int c = 0; c < 2; ++c) {                                               \
        const int q_ = c * 8 + wave;                                            \
        STG1(lds + (s) * 24576 + 16384 + q_ * 512,                              \
             Bg + (size_t)(q_ * 16 + wrow_l) * K + (j) * 32 + wcol_l);          \
    }                                                                           \
  } while (0)
#define LDA8(pa, s) do {                                                        \
    const char* a_ = (const char*)(lds + (s) * 24576);                          \
    _Pragma("unroll")                                                           \
    for (int m = 0; m < 8; ++m)                                                 \
        pa[m] = *(const bf16x8*)(a_ + abase + m * 1024);                        \
  } while (0)
#define LDB8(pb, s) do {                                                        \
    const char* b_ = (const char*)(lds + (s) * 24576 + 16384);                  \
    _Pragma("unroll")                                                           \
    for (int n = 0; n < 8; ++n)                                                 \
        pb[n] = *(const bf16x8*)(b_ + bbase + n * 1024);                        \
  } while (0)
#define MM32(pa, pb, m0) do {                                                   \
    __builtin_amdgcn_s_setprio(1);                                              \
    _Pragma("unroll")                                                           \
    for (int i = 0; i < 4; ++i)                                                 \
      _Pragma("unroll")                                                         \
      for (int n = 0; n < 8; ++n)                                               \
        acc[(m0) + i][n] = __builtin_amdgcn_mfma_f32_16x16x32_bf16(             \
            pa[(m0) + i], pb[n], acc[(m0) + i][n], 0, 0, 0);                    \
    __builtin_amdgcn_s_setprio(0);                                              \
  } while (0)
#define BAR    __builtin_amdgcn_s_barrier()
#define FENCE  asm volatile("" ::: "memory")
#define WVM(n) asm volatile("s_waitcnt vmcnt(" #n ")" ::: "memory")

    // prologue: stage units 0,1; retire unit 0; preload its regs
    STAGE(0, 0); STAGE(1, 1);
    WVM(6);                    // unit 0 resident (one ~900cy stall, once)
    BAR; FENCE;
    LDA8(paA, 0); LDB8(pbA, 0);

    // pair loop: units 0..125 (63 pairs); stages issue units 2..127
    int c0 = 0, c1 = 1, c2 = 2;
#pragma unroll 1
    for (int u = 0; u < 126; u += 2) {
        // iter u (even): MM unit u (paA/pbA), read unit u+1 -> paB/pbB
        STAGE(c2, u + 2);
        WVM(6);                // retire batch u+1 (staged last iter)
        LDA8(paB, c1);
        MM32(paA, pbA, 0);
        LDB8(pbB, c1);
        MM32(paA, pbA, 4);
        BAR; FENCE;
        { int t = c0; c0 = c1; c1 = c2; c2 = t; }
        // iter u+1 (odd): MM unit u+1 (paB/pbB), read unit u+2 -> paA/pbA
        STAGE(c2, u + 3);
        WVM(6);
        LDA8(paA, c1);
        MM32(paB, pbB, 0);
        LDB8(pbA, c1);
        MM32(paB, pbB, 4);
        BAR; FENCE;
        { int t = c0; c0 = c1; c1 = c2; c2 = t; }
    }
    // tail: units 126, 127 (no staging)
    WVM(0); BAR; FENCE;        // all stage batches done
    LDA8(paB, c1);
    MM32(paA, pbA, 0);
    LDB8(pbB, c1);
    MM32(paA, pbA, 4);         // unit 126
    MM32(paB, pbB, 0);
    MM32(paB, pbB, 4);         // unit 127

    // epilogue: C/D layout col=lane&15, row=(lane>>4)*4+reg [m89/m91]
    float bv[8];
#pragma unroll
    for (int n = 0; n < 8; ++n) bv[n] = bias[bcol + wcol + n * 16 + fr];
#pragma unroll
    for (int m = 0; m < 8; ++m) {
#pragma unroll
        for (int j = 0; j < 4; ++j) {
            const int row = brow + wrow + m * 16 + fq * 4 + j;
            float* crow = C + (size_t)row * N + bcol + wcol + fr;
#pragma unroll
            for (int n = 0; n < 8; ++n) crow[n * 16] = acc[m][n][j] + bv[n];
        }
    }
#undef STG1
#undef STAGE
#undef LDA8
#undef LDB8
#undef MM32
#undef BAR
#undef FENCE
#undef WVM
}

// ---- fallback (only if ws too small): f32 vector GEMM ----
__global__ void fallback_gemm(const float* __restrict__ x,
                              const float* __restrict__ w,
                              const int* __restrict__ mask,
                              const float* __restrict__ bias,
                              float* __restrict__ C) {
    const int tid = threadIdx.x;
    const int tx = tid & 15, ty = tid >> 4;
    const int brow = blockIdx.y * 64, bcol = blockIdx.x * 64;
    __shared__ float As[64][17];
    __shared__ float Ws[64][17];
    float acc[4][4] = {};
    for (int k0 = 0; k0 < K; k0 += 16) {
        __syncthreads();
        for (int i = tid; i < 64 * 16; i += 256) {
            int r = i >> 4, c = i & 15;
            As[r][c] = x[(size_t)(brow + r) * K + k0 + c];
            float wv = w[(size_t)(bcol + r) * K + k0 + c];
            Ws[r][c] = mask[(size_t)(bcol + r) * K + k0 + c] ? wv : 0.0f;
        }
        __syncthreads();
        for (int kk = 0; kk < 16; ++kk) {
            float a[4], b[4];
#pragma unroll
            for (int i = 0; i < 4; ++i) a[i] = As[ty * 4 + i][kk];
#pragma unroll
            for (int i = 0; i < 4; ++i) b[i] = Ws[tx * 4 + i][kk];
#pragma unroll
            for (int i = 0; i < 4; ++i)
#pragma unroll
                for (int j = 0; j < 4; ++j) acc[i][j] += a[i] * b[j];
        }
    }
    for (int i = 0; i < 4; ++i)
        for (int j = 0; j < 4; ++j) {
            int row = brow + ty * 4 + i, col = bcol + tx * 4 + j;
            C[(size_t)row * N + col] = acc[i][j] + bias[col];
        }
}

extern "C" void kernel_launch(void* const* d_in, const int* in_sizes, int n_in,
                              void* d_out, int out_size, void* d_ws, size_t ws_size,
                              hipStream_t stream) {
    const float* x    = (const float*)d_in[0];
    const float* w    = (const float*)d_in[1];
    const float* bias = (const float*)d_in[2];
    const int*   mask = (const int*)d_in[3];
    float* out = (float*)d_out;

    const size_t need = ((size_t)M * K + (size_t)N * K) * sizeof(unsigned short);
    if (ws_size >= need) {
        unsigned short* xb = (unsigned short*)d_ws;           // [M][K] bf16
        unsigned short* wb = xb + (size_t)M * K;              // [N][K] bf16
        (void)hipFuncSetAttribute((const void*)gemmW_bf16,
                                  hipFuncAttributeMaxDynamicSharedMemorySize,
                                  147456);
        cvt_x_kernel<<<(M * K / 4) / 256, 256, 0, stream>>>(x, xb);
        cvt_wm_kernel<<<(N * K / 4) / 256, 256, 0, stream>>>(w, mask, wb);
        gemmW_bf16<<<(M / BMr) * (N / BNr), 512, 147456, stream>>>(xb, wb, bias, out);
    } else {
        dim3 g(N / 64, M / 64);
        fallback_gemm<<<g, 256, 0, stream>>>(x, w, mask, bias, out);
    }
}

// Round 11
// 197.970 us; speedup vs baseline: 14.9532x; 14.9532x over previous
//
#include <hip/hip_runtime.h>
#include <hip/hip_bf16.h>
#include <stdint.h>

// ExpanderLinear: y[t,o] = sum_i x[t,i] * (w[o,i]*mask[o,i]) + bias[o]
// M=8192, K=4096, N=4096. f32 in/out. R11: INT8 MFMA path.
// Per-row symmetric i8 quant (x rows, (w*mask) rows), i32 accumulate,
// f32 dequant epilogue: y = acc * sx[t] * sw[o] + bias[o].
// GEMM = R6 structure ported to i8: 256x256 tile, 8 waves, ring-4 of
// full-K64 units [256 rows][64 B] (A 64KB + B 64KB LDS), 2 phases/K-tile,
// counted vmcnt(4), stage t+2, T1 XCD swizzle + T2 swizzle + T5 setprio.
// LDS byte layout identical to the verified bf16 kernel (rows are 64B there
// too); fragment k-map: k = fq*16 + j (contiguous-K-doubling, as bf16).

typedef __attribute__((ext_vector_type(4))) float f32x4;
typedef __attribute__((ext_vector_type(4))) int   i32x4;

static constexpr int M = 8192;
static constexpr int N = 4096;
static constexpr int K = 4096;
static constexpr int NT = K / 64;      // 64 K-tiles

#define GLOBAL_AS(p) ((const __attribute__((address_space(1))) void*)(p))
#define LDS_AS(p)    ((__attribute__((address_space(3))) void*)(p))

// ---- prep 1: per-row quant of x -> i8 + sx ----
__global__ void __launch_bounds__(256)
quant_x(const float* __restrict__ x, signed char* __restrict__ xq,
        float* __restrict__ sx) {
    const int row = blockIdx.x, tid = threadIdx.x;
    const f32x4* xr = (const f32x4*)(x + (size_t)row * K);
    f32x4 v[4];
    float am = 0.0f;
#pragma unroll
    for (int c = 0; c < 4; ++c) {
        v[c] = xr[c * 256 + tid];
        am = fmaxf(am, fmaxf(fmaxf(fabsf(v[c].x), fabsf(v[c].y)),
                             fmaxf(fabsf(v[c].z), fabsf(v[c].w))));
    }
#pragma unroll
    for (int off = 32; off; off >>= 1) am = fmaxf(am, __shfl_xor(am, off));
    __shared__ float red[4];
    if ((tid & 63) == 0) red[tid >> 6] = am;
    __syncthreads();
    am = fmaxf(fmaxf(red[0], red[1]), fmaxf(red[2], red[3]));
    const float inv = am > 0.0f ? 127.0f / am : 0.0f;
    int* out = (int*)xq + (size_t)row * (K / 4);
#pragma unroll
    for (int c = 0; c < 4; ++c) {
        int q0 = (int)__builtin_rintf(v[c].x * inv) & 255;
        int q1 = (int)__builtin_rintf(v[c].y * inv) & 255;
        int q2 = (int)__builtin_rintf(v[c].z * inv) & 255;
        int q3 = (int)__builtin_rintf(v[c].w * inv) & 255;
        out[c * 256 + tid] = q0 | (q1 << 8) | (q2 << 16) | (q3 << 24);
    }
    if (tid == 0) sx[row] = am * (1.0f / 127.0f);
}

// ---- prep 2: per-row quant of (w*mask) -> i8 + sw ----
__global__ void __launch_bounds__(256)
quant_w(const float* __restrict__ w, const int* __restrict__ mask,
        signed char* __restrict__ wq, float* __restrict__ sw) {
    const int row = blockIdx.x, tid = threadIdx.x;
    const f32x4* wr = (const f32x4*)(w + (size_t)row * K);
    const i32x4* mr = (const i32x4*)(mask + (size_t)row * K);
    f32x4 v[4];
    float am = 0.0f;
#pragma unroll
    for (int c = 0; c < 4; ++c) {
        f32x4 wv = wr[c * 256 + tid];
        i32x4 mv = mr[c * 256 + tid];
        v[c].x = mv.x ? wv.x : 0.0f;
        v[c].y = mv.y ? wv.y : 0.0f;
        v[c].z = mv.z ? wv.z : 0.0f;
        v[c].w = mv.w ? wv.w : 0.0f;
        am = fmaxf(am, fmaxf(fmaxf(fabsf(v[c].x), fabsf(v[c].y)),
                             fmaxf(fabsf(v[c].z), fabsf(v[c].w))));
    }
#pragma unroll
    for (int off = 32; off; off >>= 1) am = fmaxf(am, __shfl_xor(am, off));
    __shared__ float red[4];
    if ((tid & 63) == 0) red[tid >> 6] = am;
    __syncthreads();
    am = fmaxf(fmaxf(red[0], red[1]), fmaxf(red[2], red[3]));
    const float inv = am > 0.0f ? 127.0f / am : 0.0f;
    int* out = (int*)wq + (size_t)row * (K / 4);
#pragma unroll
    for (int c = 0; c < 4; ++c) {
        int q0 = (int)__builtin_rintf(v[c].x * inv) & 255;
        int q1 = (int)__builtin_rintf(v[c].y * inv) & 255;
        int q2 = (int)__builtin_rintf(v[c].z * inv) & 255;
        int q3 = (int)__builtin_rintf(v[c].w * inv) & 255;
        out[c * 256 + tid] = q0 | (q1 << 8) | (q2 << 16) | (q3 << 24);
    }
    if (tid == 0) sw[row] = am * (1.0f / 127.0f);
}

// ---- main GEMM (i8) ----
// LDS: A-ring = 4 units of [256 rows][64 B] (16KB each), B-ring same.
// Unit t (k bytes [64t,64t+64)) in slot t&3. Per K-tile: 2 phases:
//  P1 {LDA m0-3 (4xb128) + LDB n0-3 (4xb128), stage A(t+2) 2 gloads,
//      BAR, MM16(m0-3), BAR}
//  P2 {LDA m4-7, stage B(t+2) 2 gloads, BAR, MM16(m4-7), WVM(4), BAR}
// Swizzle within 128B row-pair: phys3 = (((row&1)<<2)|fq) ^ ((row>>1)&7);
// LDS writes linear (global_load_lds); global SOURCE pre-swizzled (s3w).
__global__ void __launch_bounds__(512, 2)
gemmI8(const signed char* __restrict__ A,   // [M][K] i8
       const signed char* __restrict__ B,   // [N][K] i8
       const float* __restrict__ sx,        // [M]
       const float* __restrict__ sw,        // [N]
       const float* __restrict__ bias,      // [N]
       float* __restrict__ C) {             // [M][N] f32
    extern __shared__ unsigned char lds[];
    unsigned char* __restrict__ Au = lds;            // 4 * 16384 B
    unsigned char* __restrict__ Bu = lds + 65536;    // 4 * 16384 B

    const int tid  = threadIdx.x;
    const int lane = tid & 63;
    const int wave = tid >> 6;

    // T1: XCD-aware bijective swizzle (nwg = 512, % 8 == 0)
    const int bid = blockIdx.x;
    const int swz = (bid & 7) * 64 + (bid >> 3);
    const int brow = (swz >> 4) * 256;         // ntn = 16
    const int bcol = (swz & 15) * 256;

    const int wrow = (wave >> 2) * 128;        // wave output rows
    const int wcol = (wave & 3) * 64;          // wave output cols
    const int fr = lane & 15;                  // fragment row/col
    const int fq = lane >> 4;                  // k-subgroup (16B each)

    // read-side swizzle bases (byte offsets within a 16KB unit)
    const int s3r   = (((fr & 1) << 2) | fq) ^ (fr >> 1);
    const int abase = wrow * 64 + (fr >> 1) * 128 + s3r * 16;   // + m*1024
    const int bbase = wcol * 64 + (fr >> 1) * 128 + s3r * 16;   // + n*1024

    // write-side: lane's linear LDS slot -> logical (row, byte-col) in global
    const int l8 = lane & 7, lh = lane >> 3;
    const int s3w    = l8 ^ lh;
    const int wrow_l = 2 * lh + (s3w >> 2);    // row within 16-row chunk
    const int wcol_b = (s3w & 3) * 16;         // byte col within 64-B row

    const signed char* __restrict__ Ag = A + (size_t)brow * K;
    const signed char* __restrict__ Bg = B + (size_t)bcol * K;

    i32x4 acc[8][4];
#pragma unroll
    for (int m = 0; m < 8; ++m)
#pragma unroll
        for (int n = 0; n < 4; ++n) acc[m][n] = (i32x4)(0);

    i32x4 afL[4], afH[4], bfv[4];

#define STG1(dst, src) __builtin_amdgcn_global_load_lds(GLOBAL_AS(src), LDS_AS(dst), 16, 0, 0)
#define STGA(slot, j) do {                                                      \
    _Pragma("unroll")                                                           \
    for (int c = 0; c < 2; ++c) {                                               \
        const int q_ = c * 8 + wave;                                            \
        STG1(Au + (slot) * 16384 + q_ * 1024,                                   \
             Ag + (size_t)(q_ * 16 + wrow_l) * K + (j) * 64 + wcol_b);          \
    }                                                                           \
  } while (0)
#define STGB(slot, j) do {                                                      \
    _Pragma("unroll")                                                           \
    for (int c = 0; c < 2; ++c) {                                               \
        const int q_ = c * 8 + wave;                                            \
        STG1(Bu + (slot) * 16384 + q_ * 1024,                                   \
             Bg + (size_t)(q_ * 16 + wrow_l) * K + (j) * 64 + wcol_b);          \
    }                                                                           \
  } while (0)
#define LDA4(buf, unit, m0) do {                                                \
    const unsigned char* ub_ = Au + (unit) * 16384;                             \
    _Pragma("unroll")                                                           \
    for (int i = 0; i < 4; ++i)                                                 \
        buf[i] = *(const i32x4*)(ub_ + abase + ((m0) + i) * 1024);              \
  } while (0)
#define LDB4(buf, unit) do {                                                    \
    const unsigned char* vb_ = Bu + (unit) * 16384;                             \
    _Pragma("unroll")                                                           \
    for (int n = 0; n < 4; ++n)                                                 \
        buf[n] = *(const i32x4*)(vb_ + bbase + n * 1024);                       \
  } while (0)
#define MM16(a, r0) do {                                                        \
    __builtin_amdgcn_s_setprio(1);                                              \
    _Pragma("unroll")                                                           \
    for (int i = 0; i < 4; ++i)                                                 \
      _Pragma("unroll")                                                         \
      for (int n = 0; n < 4; ++n)                                               \
        acc[(r0) + i][n] = __builtin_amdgcn_mfma_i32_16x16x64_i8(               \
            a[i], bfv[n], acc[(r0) + i][n], 0, 0, 0);                           \
    __builtin_amdgcn_s_setprio(0);                                              \
  } while (0)
#define BAR    __builtin_amdgcn_s_barrier()
#define FENCE  asm volatile("" ::: "memory")
#define WVM4   asm volatile("s_waitcnt vmcnt(4)" ::: "memory")
#define WVM0   asm volatile("s_waitcnt vmcnt(0)" ::: "memory")

    // prologue: stage tiles 0,1 (A+B each); retire tile 0 (8 -> 4 outstanding)
    STGA(0, 0); STGB(0, 0);
    STGA(1, 1); STGB(1, 1);
    WVM4;
    BAR; FENCE;

#pragma unroll 1
    for (int t = 0; t < NT - 2; ++t) {
        const int u  = t & 3;
        const int s2 = (t + 2) & 3;
        // P1
        LDA4(afL, u, 0); LDB4(bfv, u);
        STGA(s2, t + 2);
        BAR; FENCE;
        MM16(afL, 0);
        BAR; FENCE;
        // P2
        LDA4(afH, u, 4);
        STGB(s2, t + 2);
        BAR; FENCE;
        MM16(afH, 4);
        WVM4;                 // retires tile t+1's 4-gload batch
        BAR; FENCE;
    }
    {   // tile NT-2: no staging; drain tile NT-1's batch at end
        const int u = (NT - 2) & 3;
        LDA4(afL, u, 0); LDB4(bfv, u);
        BAR; FENCE;
        MM16(afL, 0);
        BAR; FENCE;
        LDA4(afH, u, 4);
        BAR; FENCE;
        MM16(afH, 4);
        WVM0;
        BAR; FENCE;
    }
    {   // tile NT-1: no staging, no waits after
        const int u = (NT - 1) & 3;
        LDA4(afL, u, 0); LDB4(bfv, u);
        BAR; FENCE;
        MM16(afL, 0);
        BAR; FENCE;
        LDA4(afH, u, 4);
        FENCE;
        MM16(afH, 4);
    }

    // epilogue: C/D layout col=lane&15, row=(lane>>4)*4+reg (dtype-indep,
    // m121-m128); y = acc * sx[row]*sw[col] + bias[col]
    float swv[4], bvv[4];
#pragma unroll
    for (int n = 0; n < 4; ++n) {
        const int col = bcol + wcol + n * 16 + fr;
        swv[n] = sw[col];
        bvv[n] = bias[col];
    }
#pragma unroll
    for (int m = 0; m < 8; ++m) {
#pragma unroll
        for (int j = 0; j < 4; ++j) {
            const int row = brow + wrow + m * 16 + fq * 4 + j;
            const float sxr = sx[row];
            float* crow = C + (size_t)row * N + bcol + wcol + fr;
#pragma unroll
            for (int n = 0; n < 4; ++n)
                crow[n * 16] = (float)acc[m][n][j] * (sxr * swv[n]) + bvv[n];
        }
    }
#undef STG1
#undef STGA
#undef STGB
#undef LDA4
#undef LDB4
#undef MM16
#undef BAR
#undef FENCE
#undef WVM4
#undef WVM0
}

// ---- fallback (only if ws too small): f32 vector GEMM ----
__global__ void fallback_gemm(const float* __restrict__ x,
                              const float* __restrict__ w,
                              const int* __restrict__ mask,
                              const float* __restrict__ bias,
                              float* __restrict__ C) {
    const int tid = threadIdx.x;
    const int tx = tid & 15, ty = tid >> 4;
    const int brow = blockIdx.y * 64, bcol = blockIdx.x * 64;
    __shared__ float As[64][17];
    __shared__ float Ws[64][17];
    float acc[4][4] = {};
    for (int k0 = 0; k0 < K; k0 += 16) {
        __syncthreads();
        for (int i = tid; i < 64 * 16; i += 256) {
            int r = i >> 4, c = i & 15;
            As[r][c] = x[(size_t)(brow + r) * K + k0 + c];
            float wv = w[(size_t)(bcol + r) * K + k0 + c];
            Ws[r][c] = mask[(size_t)(bcol + r) * K + k0 + c] ? wv : 0.0f;
        }
        __syncthreads();
        for (int kk = 0; kk < 16; ++kk) {
            float a[4], b[4];
#pragma unroll
            for (int i = 0; i < 4; ++i) a[i] = As[ty * 4 + i][kk];
#pragma unroll
            for (int i = 0; i < 4; ++i) b[i] = Ws[tx * 4 + i][kk];
#pragma unroll
            for (int i = 0; i < 4; ++i)
#pragma unroll
                for (int j = 0; j < 4; ++j) acc[i][j] += a[i] * b[j];
        }
    }
    for (int i = 0; i < 4; ++i)
        for (int j = 0; j < 4; ++j) {
            int row = brow + ty * 4 + i, col = bcol + tx * 4 + j;
            C[(size_t)row * N + col] = acc[i][j] + bias[col];
        }
}

extern "C" void kernel_launch(void* const* d_in, const int* in_sizes, int n_in,
                              void* d_out, int out_size, void* d_ws, size_t ws_size,
                              hipStream_t stream) {
    const float* x    = (const float*)d_in[0];
    const float* w    = (const float*)d_in[1];
    const float* bias = (const float*)d_in[2];
    const int*   mask = (const int*)d_in[3];
    float* out = (float*)d_out;

    const size_t xq_b = (size_t)M * K;              // 32 MiB
    const size_t wq_b = (size_t)N * K;              // 16 MiB
    const size_t need = xq_b + wq_b + (M + N) * sizeof(float);
    if (ws_size >= need) {
        signed char* xq = (signed char*)d_ws;
        signed char* wq = xq + xq_b;
        float* sx = (float*)(wq + wq_b);
        float* sw = sx + M;
        (void)hipFuncSetAttribute((const void*)gemmI8,
                                  hipFuncAttributeMaxDynamicSharedMemorySize,
                                  131072);
        quant_x<<<M, 256, 0, stream>>>(x, xq, sx);
        quant_w<<<N, 256, 0, stream>>>(w, mask, wq, sw);
        gemmI8<<<(M / 256) * (N / 256), 512, 131072, stream>>>(
            xq, wq, sx, sw, bias, out);
    } else {
        dim3 g(N / 64, M / 64);
        fallback_gemm<<<g, 256, 0, stream>>>(x, w, mask, bias, out);
    }
}